// Round 1
// baseline (33.695 us; speedup 1.0000x reference)
//
#include <hip/hip_runtime.h>

#define NB 32
#define NS 8192
#define ND 64
#define CHUNK 256
#define NCHUNK (NS / CHUNK)   // 32
#define INV_T 0.125f          // 1/8.0
#define PSTRIDE 66            // m, l, acc[64]

// ---------------- Phase 1: per-(batch, S-chunk) partial flash attention ----
__global__ __launch_bounds__(256) void attn_p1(
    const float* __restrict__ q, const float* __restrict__ k,
    const float* __restrict__ v, float* __restrict__ attn,
    float* __restrict__ part)
{
    const int blk = blockIdx.x;       // 0 .. NB*NCHUNK-1
    const int b   = blk >> 5;         // / NCHUNK
    const int c   = blk & (NCHUNK - 1);
    const int tid = threadIdx.x;
    const int w   = tid >> 6;         // wave 0..3
    const int l   = tid & 63;         // lane
    const int l16 = l & 15;           // lane within 16-group (owns 4 dims)
    const int g   = l >> 4;           // group 0..3 within wave

    // q fragment: lane16 owns dims [l16*4, l16*4+4)
    const float4 qv = *reinterpret_cast<const float4*>(q + b * ND + l16 * 4);

    const size_t kb = (size_t)b * NS * ND;
    const int rows_base = c * CHUNK + w * 64 + g * 16;   // this group's 16 rows

    // ---- scores: each 16-lane group does 16 rows, coalesced float4 reads
    float s[16];
#pragma unroll
    for (int i = 0; i < 16; ++i) {
        const float4 kv = *reinterpret_cast<const float4*>(
            k + kb + (size_t)(rows_base + i) * ND + l16 * 4);
        float p = qv.x * kv.x + qv.y * kv.y + qv.z * kv.z + qv.w * kv.w;
        p += __shfl_xor(p, 1);
        p += __shfl_xor(p, 2);
        p += __shfl_xor(p, 4);
        p += __shfl_xor(p, 8);   // all 16 lanes of group now hold full dot
        s[i] = p * INV_T;
    }

    // raw scores -> final attn region (coalesced: thread tid owns local row tid,
    // since tid = w*64 + g*16 + l16 and that row's score is s[l16])
    attn[(size_t)b * NS + c * CHUNK + tid] = s[l16];

    // ---- chunk max
    float m = s[0];
#pragma unroll
    for (int i = 1; i < 16; ++i) m = fmaxf(m, s[i]);

    __shared__ float redm[16];
    __shared__ float redl[16];
    __shared__ float accl[4][ND];

    if (l16 == 0) redm[w * 4 + g] = m;
    __syncthreads();
    float mc = redm[0];
#pragma unroll
    for (int i = 1; i < 16; ++i) mc = fmaxf(mc, redm[i]);

    // ---- l_c and partial sum(e * v)
    float lsum = 0.f;
    float4 acc = make_float4(0.f, 0.f, 0.f, 0.f);
#pragma unroll
    for (int i = 0; i < 16; ++i) {
        const float e = __expf(s[i] - mc);
        lsum += e;
        const float4 vv = *reinterpret_cast<const float4*>(
            v + kb + (size_t)(rows_base + i) * ND + l16 * 4);
        acc.x += e * vv.x; acc.y += e * vv.y;
        acc.z += e * vv.z; acc.w += e * vv.w;
    }

    if (l16 == 0) redl[w * 4 + g] = lsum;

    // reduce acc across the 4 groups of the wave (same dims, different rows)
    acc.x += __shfl_xor(acc.x, 16); acc.y += __shfl_xor(acc.y, 16);
    acc.z += __shfl_xor(acc.z, 16); acc.w += __shfl_xor(acc.w, 16);
    acc.x += __shfl_xor(acc.x, 32); acc.y += __shfl_xor(acc.y, 32);
    acc.z += __shfl_xor(acc.z, 32); acc.w += __shfl_xor(acc.w, 32);
    if (l < 16) {
        accl[w][l16 * 4 + 0] = acc.x;
        accl[w][l16 * 4 + 1] = acc.y;
        accl[w][l16 * 4 + 2] = acc.z;
        accl[w][l16 * 4 + 3] = acc.w;
    }
    __syncthreads();

    float* pp = part + (size_t)blk * PSTRIDE;
    if (tid == 0) {
        float lt = 0.f;
        for (int i = 0; i < 16; ++i) lt += redl[i];
        pp[0] = mc;
        pp[1] = lt;
    }
    if (tid < ND) {
        pp[2 + tid] = accl[0][tid] + accl[1][tid] + accl[2][tid] + accl[3][tid];
    }
}

// ---------------- Phase 2: reduce chunk partials per batch ---------------
__global__ __launch_bounds__(64) void attn_p2(
    const float* __restrict__ part, float* __restrict__ out,
    float* __restrict__ stats)
{
    const int b = blockIdx.x;
    const int t = threadIdx.x;           // dim 0..63
    const float* pb = part + (size_t)b * NCHUNK * PSTRIDE;

    float m = -1e30f;
    for (int c = 0; c < NCHUNK; ++c) m = fmaxf(m, pb[c * PSTRIDE]);

    float lsum = 0.f, acc = 0.f;
    for (int c = 0; c < NCHUNK; ++c) {
        const float wgt = __expf(pb[c * PSTRIDE] - m);
        lsum += pb[c * PSTRIDE + 1] * wgt;
        acc  += pb[c * PSTRIDE + 2 + t] * wgt;
    }
    const float invl = 1.f / lsum;
    out[b * ND + t] = acc * invl;
    if (t == 0) { stats[b * 2] = m; stats[b * 2 + 1] = invl; }
}

// ---------------- Phase 3: rescale raw scores -> probabilities -----------
__global__ __launch_bounds__(256) void attn_p3(
    float* __restrict__ attn, const float* __restrict__ stats)
{
    const int idx = blockIdx.x * 256 + threadIdx.x;  // over NB*NS/4 float4s
    const int b = idx >> 11;                         // NS/4 = 2048 per batch
    const float m    = stats[b * 2];
    const float invl = stats[b * 2 + 1];
    float4 sv = reinterpret_cast<float4*>(attn)[idx];
    sv.x = __expf(sv.x - m) * invl;
    sv.y = __expf(sv.y - m) * invl;
    sv.z = __expf(sv.z - m) * invl;
    sv.w = __expf(sv.w - m) * invl;
    reinterpret_cast<float4*>(attn)[idx] = sv;
}

extern "C" void kernel_launch(void* const* d_in, const int* in_sizes, int n_in,
                              void* d_out, int out_size, void* d_ws, size_t ws_size,
                              hipStream_t stream)
{
    const float* q = (const float*)d_in[0];   // [32, 64]
    const float* k = (const float*)d_in[1];   // [32, 8192, 64]
    const float* v = (const float*)d_in[2];   // [32, 8192, 64]

    float* out  = (float*)d_out;              // [32,1,64]  -> 2048 floats
    float* attn = out + NB * ND;              // [32,1,8192]-> 262144 floats

    float* part  = (float*)d_ws;                       // [NB*NCHUNK][66]
    float* stats = part + (size_t)NB * NCHUNK * PSTRIDE; // [NB][2]

    attn_p1<<<NB * NCHUNK, 256, 0, stream>>>(q, k, v, attn, part);
    attn_p2<<<NB, 64, 0, stream>>>(part, out, stats);
    attn_p3<<<(NB * NS / 4) / 256, 256, 0, stream>>>(attn, stats);
}